// Round 2
// baseline (196.291 us; speedup 1.0000x reference)
//
#include <hip/hip_runtime.h>
#include <hip/hip_bf16.h>

// MHA fwd: B=2, S=2048, D=1024, H=16, HD=64. fp32 in/out, bf16 MFMA internals.
// R10: attention k-tiles widened 64->128 (36 MFMA per barrier-pair, iters
// halved 33->17). LDS 49.4 KB -> 3 blocks/CU. XCD-pinned big-first grid.
// R12: GEMM tiles widened to the m97-verified geometry:
//   gemm_qkv 128x64 -> 128x128 (acc[4][4], 32 MFMA / 8 glds per BK=64 step,
//     grid 32x8x3 = 768 blocks = exactly 3 blocks/CU residency)
//   gemm_out 64x64 -> 128x64 (the old qkv structure; 512 blocks = 2/CU)
// Attention unchanged from R10.

typedef __bf16 bf16x8 __attribute__((ext_vector_type(8)));
typedef float f32x4 __attribute__((ext_vector_type(4)));

#define S_LEN 2048
#define DMODEL 1024
#define NHEAD 16
#define HDIM 64
#define MROWS 4096  // B*S

#define AS1 __attribute__((address_space(1)))
#define AS3 __attribute__((address_space(3)))

#define QSCALE 0.18033688f  // 0.125 * log2e: scores come out in log2 units
#define LDP 136             // Ps row pitch (bf16): 272 B = 17x16B

// ---------------- cast x (fp32 -> bf16), 4 elems/thread ----------------
__global__ void cast_x_kernel(const float* __restrict__ X, __bf16* __restrict__ Xb) {
    int i = (blockIdx.x * blockDim.x + threadIdx.x) * 4;
    float4 f = *(const float4*)&X[i];
    Xb[i + 0] = (__bf16)f.x;
    Xb[i + 1] = (__bf16)f.y;
    Xb[i + 2] = (__bf16)f.z;
    Xb[i + 3] = (__bf16)f.w;
}

// ------------- transpose + cast all 4 weights: WT[n][k] = W[k][n] -------------
__global__ void transpose_cast_kernel(
    const float* __restrict__ W0, const float* __restrict__ W1,
    const float* __restrict__ W2, const float* __restrict__ W3,
    __bf16* __restrict__ T0, __bf16* __restrict__ T1,
    __bf16* __restrict__ T2, __bf16* __restrict__ T3) {
    const float* W = (blockIdx.z == 0) ? W0 : (blockIdx.z == 1) ? W1 : (blockIdx.z == 2) ? W2 : W3;
    __bf16* WT = (blockIdx.z == 0) ? T0 : (blockIdx.z == 1) ? T1 : (blockIdx.z == 2) ? T2 : T3;
    __shared__ float tile[32][33];
    int bx = blockIdx.x, by = blockIdx.y;
    int tx = threadIdx.x;
    for (int i = threadIdx.y; i < 32; i += 8)
        tile[i][tx] = W[(size_t)(by * 32 + i) * DMODEL + bx * 32 + tx];
    __syncthreads();
    for (int i = threadIdx.y; i < 32; i += 8)
        WT[(size_t)(bx * 32 + i) * DMODEL + by * 32 + tx] = (__bf16)tile[tx][i];
}

// ------------- GEMM QKV: 128x128 tile, BK=64, glds(16B) + XOR swizzle --------
// m97 geometry: per wave 64x64 out, acc[4][4], 32 MFMA + 16 ds_read_b128 +
// 8 glds per BK=64 K-step. Grid (32, 8, 3) = 768 blocks = 3/CU.
__global__ __launch_bounds__(256) void gemm_qkv_kernel(
    const __bf16* __restrict__ X,
    const __bf16* __restrict__ WqT, const __bf16* __restrict__ WkT, const __bf16* __restrict__ WvT,
    const float* __restrict__ bq, const float* __restrict__ bk, const float* __restrict__ bv,
    __bf16* __restrict__ Q, __bf16* __restrict__ K, __bf16* __restrict__ Vt) {
    const int which = blockIdx.z;
    const __bf16* Bt = (which == 0) ? WqT : (which == 1) ? WkT : WvT;
    const float* bias = (which == 0) ? bq : (which == 1) ? bk : bv;
    __bf16* Out = (which == 0) ? Q : (which == 1) ? K : Vt;

    __shared__ alignas(16) __bf16 As[128 * 64];
    __shared__ alignas(16) __bf16 Bs[128 * 64];

    const int tid = threadIdx.x;
    const int lane = tid & 63;
    const int wave = tid >> 6;
    const int wm = wave >> 1, wn = wave & 1;
    const int quad = lane >> 4;
    const int l16 = lane & 15;
    const int m0 = blockIdx.x * 128;   // m-tile on x (XCD locality)
    const int n0 = blockIdx.y * 128;
    const int r8 = lane >> 3;
    const int sc8 = ((lane & 7) ^ r8) * 8;
    const int gq0 = ((0 + quad) ^ (l16 & 7)) * 8;
    const int gq1 = ((4 + quad) ^ (l16 & 7)) * 8;

    f32x4 acc[4][4] = {};

    for (int k0 = 0; k0 < DMODEL; k0 += 64) {
        __syncthreads();
#pragma unroll
        for (int p = 0; p < 4; p++) {  // A: 128 rows, 8 rows/glds
            const int row = wave * 32 + p * 8;
            __builtin_amdgcn_global_load_lds(
                (const AS1 void*)&X[(size_t)(m0 + row + r8) * DMODEL + k0 + sc8],
                (AS3 void*)&As[row * 64], 16, 0, 0);
        }
#pragma unroll
        for (int p = 0; p < 4; p++) {  // B: 128 rows, 8 rows/glds
            const int row = wave * 32 + p * 8;
            __builtin_amdgcn_global_load_lds(
                (const AS1 void*)&Bt[(size_t)(n0 + row + r8) * DMODEL + k0 + sc8],
                (AS3 void*)&Bs[row * 64], 16, 0, 0);
        }
        __syncthreads();
#pragma unroll
        for (int ks = 0; ks < 2; ks++) {
            const int g = ks ? gq1 : gq0;
            bf16x8 af[4], bfr[4];
#pragma unroll
            for (int t = 0; t < 4; t++)
                af[t] = *(bf16x8*)&As[(wm * 64 + t * 16 + l16) * 64 + g];
#pragma unroll
            for (int t = 0; t < 4; t++)
                bfr[t] = *(bf16x8*)&Bs[(wn * 64 + t * 16 + l16) * 64 + g];
#pragma unroll
            for (int mt = 0; mt < 4; mt++)
#pragma unroll
                for (int nt = 0; nt < 4; nt++)
                    acc[mt][nt] = __builtin_amdgcn_mfma_f32_16x16x32_bf16(af[mt], bfr[nt], acc[mt][nt], 0, 0, 0);
        }
    }

    // C/D layout: col = lane&15, row = quad*4 + reg  [m89-verified]
#pragma unroll
    for (int mt = 0; mt < 4; mt++)
#pragma unroll
        for (int nt = 0; nt < 4; nt++) {
            const int n = n0 + wn * 64 + nt * 16 + l16;
            const float bn = bias[n];
            const int h = n >> 6, hd = n & 63;
            const int mbase = m0 + wm * 64 + mt * 16 + quad * 4;
            if (which == 2) {
                __bf16 pk[4];
#pragma unroll
                for (int r = 0; r < 4; r++) pk[r] = (__bf16)(acc[mt][nt][r] + bn);
                const int m = mbase;
                const int b = m >> 11, s = m & 2047;
                *(uint2*)&Out[(((size_t)(b * NHEAD + h) * HDIM + hd) * S_LEN) + s] = *(uint2*)pk;
            } else {
                const float sc = (which == 0) ? QSCALE : 1.0f;  // Q: fold 1/8 * log2e
#pragma unroll
                for (int r = 0; r < 4; r++) {
                    const int m = mbase + r;
                    const int b = m >> 11, s = m & 2047;
                    Out[(((size_t)(b * NHEAD + h) * S_LEN + s) * HDIM) + hd] =
                        (__bf16)((acc[mt][nt][r] + bn) * sc);
                }
            }
        }
}

// ------------- GEMM OUT: 128x64 tile, BK=64, grid (32,16): m-tile on x -------
__global__ __launch_bounds__(256) void gemm_out_kernel(
    const __bf16* __restrict__ A, const __bf16* __restrict__ Bt,
    const float* __restrict__ bias, float* __restrict__ Y) {
    __shared__ alignas(16) __bf16 As[128 * 64];
    __shared__ alignas(16) __bf16 Bs[64 * 64];

    const int tid = threadIdx.x;
    const int lane = tid & 63;
    const int wave = tid >> 6;
    const int wm = wave >> 1, wn = wave & 1;
    const int quad = lane >> 4;
    const int l16 = lane & 15;
    const int m0 = blockIdx.x * 128;   // m-tile on x (XCD locality)
    const int n0 = blockIdx.y * 64;
    const int r8 = lane >> 3;
    const int sc8 = ((lane & 7) ^ r8) * 8;
    const int gq0 = ((0 + quad) ^ (l16 & 7)) * 8;
    const int gq1 = ((4 + quad) ^ (l16 & 7)) * 8;

    f32x4 acc[4][2] = {};

    for (int k0 = 0; k0 < DMODEL; k0 += 64) {
        __syncthreads();
#pragma unroll
        for (int p = 0; p < 4; p++) {  // A: 128 rows
            const int row = wave * 32 + p * 8;
            __builtin_amdgcn_global_load_lds(
                (const AS1 void*)&A[(size_t)(m0 + row + r8) * DMODEL + k0 + sc8],
                (AS3 void*)&As[row * 64], 16, 0, 0);
        }
#pragma unroll
        for (int p = 0; p < 2; p++) {  // B: 64 rows
            const int row = wave * 16 + p * 8;
            __builtin_amdgcn_global_load_lds(
                (const AS1 void*)&Bt[(size_t)(n0 + row + r8) * DMODEL + k0 + sc8],
                (AS3 void*)&Bs[row * 64], 16, 0, 0);
        }
        __syncthreads();
#pragma unroll
        for (int ks = 0; ks < 2; ks++) {
            const int g = ks ? gq1 : gq0;
            bf16x8 af[4], bfr[2];
#pragma unroll
            for (int t = 0; t < 4; t++)
                af[t] = *(bf16x8*)&As[(wm * 64 + t * 16 + l16) * 64 + g];
#pragma unroll
            for (int t = 0; t < 2; t++)
                bfr[t] = *(bf16x8*)&Bs[(wn * 32 + t * 16 + l16) * 64 + g];
#pragma unroll
            for (int mt = 0; mt < 4; mt++)
#pragma unroll
                for (int nt = 0; nt < 2; nt++)
                    acc[mt][nt] = __builtin_amdgcn_mfma_f32_16x16x32_bf16(af[mt], bfr[nt], acc[mt][nt], 0, 0, 0);
        }
    }

#pragma unroll
    for (int mt = 0; mt < 4; mt++)
#pragma unroll
        for (int nt = 0; nt < 2; nt++)
#pragma unroll
            for (int r = 0; r < 4; r++) {
                int m = m0 + wm * 64 + mt * 16 + quad * 4 + r;
                int n = n0 + wn * 32 + nt * 16 + l16;
                Y[(size_t)m * DMODEL + n] = acc[mt][nt][r] + bias[n];
            }
}

// -------- flash attention (R10: 128-wide k-tiles) ----------------------------
// Ks[128 k-rows][64 hd], Vs[64 hd][128 k-cols], Ps pitch 136. One tile =
// up-to-8 k-subtiles (nt): 16 QK + 16 PV + 4 ones MFMA per wave per barrier
// pair. NT=4 instantiation handles the trailing half tile of even qt.
// p = exp2(score) directly (Q pre-scaled by 0.125*log2e; o/l scale-invariant).

template <int NT>
__device__ __forceinline__ void attn_tile(
    const __bf16* Ks, const __bf16* Vs, __bf16* Psw,
    const bf16x8& qf0, const bf16x8& qf1, const bf16x8& onef,
    f32x4 (&oacc)[4], f32x4& lacc,
    int q0, int k0, bool mask, int wave, int quad, int l16, int g0, int g1) {
    f32x4 sacc[NT];
#pragma unroll
    for (int nt = 0; nt < NT; nt++) sacc[nt] = (f32x4){0.f, 0.f, 0.f, 0.f};
#pragma unroll
    for (int nt = 0; nt < NT; nt++) {
        const int krow = (nt * 16 + l16) * 64;
        bf16x8 kf0 = *(bf16x8*)&Ks[krow + g0];
        bf16x8 kf1 = *(bf16x8*)&Ks[krow + g1];
        sacc[nt] = __builtin_amdgcn_mfma_f32_16x16x32_bf16(qf0, kf0, sacc[nt], 0, 0, 0);
        sacc[nt] = __builtin_amdgcn_mfma_f32_16x16x32_bf16(qf1, kf1, sacc[nt], 0, 0, 0);
    }
    if (mask) {
#pragma unroll
        for (int nt = 0; nt < NT; nt++)
#pragma unroll
            for (int r = 0; r < 4; r++) {
                const int kcol = k0 + nt * 16 + l16;
                const int qg = q0 + wave * 16 + quad * 4 + r;
                float p = (kcol > qg) ? 0.0f : __builtin_amdgcn_exp2f(sacc[nt][r]);
                Psw[(quad * 4 + r) * LDP + nt * 16 + l16] = (__bf16)p;
            }
    } else {
#pragma unroll
        for (int nt = 0; nt < NT; nt++)
#pragma unroll
            for (int r = 0; r < 4; r++)
                Psw[(quad * 4 + r) * LDP + nt * 16 + l16] =
                    (__bf16)__builtin_amdgcn_exp2f(sacc[nt][r]);
    }
#pragma unroll
    for (int ks = 0; ks < NT / 2; ks++) {
        bf16x8 pf = *(bf16x8*)&Psw[l16 * LDP + ks * 32 + quad * 8];
        const int vg = (((ks * 4 + quad) ^ (l16 & 7)) * 8);
#pragma unroll
        for (int nt2 = 0; nt2 < 4; nt2++) {
            bf16x8 vf = *(bf16x8*)&Vs[(nt2 * 16 + l16) * 128 + vg];
            oacc[nt2] = __builtin_amdgcn_mfma_f32_16x16x32_bf16(pf, vf, oacc[nt2], 0, 0, 0);
        }
        lacc = __builtin_amdgcn_mfma_f32_16x16x32_bf16(pf, onef, lacc, 0, 0, 0);
    }
}

__global__ __launch_bounds__(256, 3) void attn_kernel(
    const __bf16* __restrict__ Q, const __bf16* __restrict__ K, const __bf16* __restrict__ Vt,
    __bf16* __restrict__ Aout) {
    const int id = blockIdx.x;
    const int bh = id & 31;                 // XCD-pinned: id%8 == bh%8
    const int qt = 31 - (id >> 5);          // big tiles first
    const int b = bh >> 4, h = bh & 15;
    const int tid = threadIdx.x, lane = tid & 63, wave = tid >> 6;
    const int quad = lane >> 4, l16 = lane & 15;

    __shared__ alignas(16) __bf16 Ks[128 * 64];
    __shared__ alignas(16) __bf16 Vs[64 * 128];
    __shared__ alignas(16) __bf16 Ps[4][16 * LDP];

    const size_t base = (size_t)bh * S_LEN * HDIM;   // same for K and Vt
    const int q0 = qt * 64;
    const int qrow = q0 + wave * 16 + l16;

    bf16x8 qf0 = *(const bf16x8*)&Q[base + (size_t)qrow * HDIM + quad * 8];
    bf16x8 qf1 = *(const bf16x8*)&Q[base + (size_t)qrow * HDIM + 32 + quad * 8];

    bf16x8 onef;
#pragma unroll
    for (int jj = 0; jj < 8; jj++) onef[jj] = (__bf16)1.0f;

    f32x4 oacc[4] = {};
    f32x4 lacc = {};
    __bf16* Psw = &Ps[wave][0];

    // staging lane roles
    const int r8k = lane >> 3;
    const int sck = ((lane & 7) ^ r8k) * 8;          // K source chunk (elems)
    const int r4v = lane >> 4;                        // V: 4 rows per glds
    // fragment-read granules (Ks pitch 64)
    const int g0 = (quad ^ (l16 & 7)) * 8;
    const int g1 = g0 ^ 32;

    const int kb_all = (qt >> 1) + 1;
    for (int kb = 0; kb < kb_all; kb++) {
        const int k0 = kb * 128;
        __syncthreads();
#pragma unroll
        for (int p = 0; p < 4; p++) {  // K: 128 rows, 8 rows/glds
            const int row = wave * 32 + p * 8;
            __builtin_amdgcn_global_load_lds(
                (const AS1 void*)&K[base + (size_t)(k0 + row + r8k) * HDIM + sck],
                (AS3 void*)&Ks[row * 64], 16, 0, 0);
        }
#pragma unroll
        for (int p = 0; p < 4; p++) {  // V^T: 64 rows x 128 cols, 4 rows/glds
            const int row = wave * 16 + p * 4;
            const int lc = ((lane & 15) ^ ((p * 4 + r4v) & 7)) * 8;
            __builtin_amdgcn_global_load_lds(
                (const AS1 void*)&Vt[base + (size_t)(row + r4v) * S_LEN + k0 + lc],
                (AS3 void*)&Vs[row * 128], 16, 0, 0);
        }
        __syncthreads();

        const bool last = (kb == kb_all - 1);
        if (!last)
            attn_tile<8>(Ks, Vs, Psw, qf0, qf1, onef, oacc, lacc, q0, k0, false,
                         wave, quad, l16, g0, g1);
        else if (qt & 1)
            attn_tile<8>(Ks, Vs, Psw, qf0, qf1, onef, oacc, lacc, q0, k0, true,
                         wave, quad, l16, g0, g1);
        else
            attn_tile<4>(Ks, Vs, Psw, qf0, qf1, onef, oacc, lacc, q0, k0, true,
                         wave, quad, l16, g0, g1);
    }

    float rl[4];
#pragma unroll
    for (int r = 0; r < 4; r++) rl[r] = 1.0f / lacc[r];
#pragma unroll
    for (int nt2 = 0; nt2 < 4; nt2++)
#pragma unroll
        for (int r = 0; r < 4; r++) {
            int qg = q0 + wave * 16 + quad * 4 + r;
            int col = h * HDIM + nt2 * 16 + l16;
            Aout[(size_t)(b * S_LEN + qg) * DMODEL + col] = (__bf16)(oacc[nt2][r] * rl[r]);
        }
}

extern "C" void kernel_launch(void* const* d_in, const int* in_sizes, int n_in,
                              void* d_out, int out_size, void* d_ws, size_t ws_size,
                              hipStream_t stream) {
    const float* x  = (const float*)d_in[0];
    // d_in[1] = mask: causal triu, reproduced analytically
    const float* wq = (const float*)d_in[2];
    const float* bq = (const float*)d_in[3];
    const float* wk = (const float*)d_in[4];
    const float* bk = (const float*)d_in[5];
    const float* wv = (const float*)d_in[6];
    const float* bv = (const float*)d_in[7];
    const float* wo = (const float*)d_in[8];
    const float* bo = (const float*)d_in[9];
    float* out = (float*)d_out;

    char* ws = (char*)d_ws;
    __bf16* xb  = (__bf16*)(ws);                          // 8 MiB
    __bf16* wqT = (__bf16*)(ws + ((size_t)8  << 20));     // 2 MiB each
    __bf16* wkT = (__bf16*)(ws + ((size_t)10 << 20));
    __bf16* wvT = (__bf16*)(ws + ((size_t)12 << 20));
    __bf16* woT = (__bf16*)(ws + ((size_t)14 << 20));
    __bf16* Qb  = (__bf16*)(ws + ((size_t)16 << 20));     // 8 MiB each
    __bf16* Kb  = (__bf16*)(ws + ((size_t)24 << 20));
    __bf16* Vtb = (__bf16*)(ws + ((size_t)32 << 20));     // V^T [B,H,HD,S]
    __bf16* Ab  = (__bf16*)(ws + ((size_t)40 << 20));     // 8 MiB

    cast_x_kernel<<<4096, 256, 0, stream>>>(x, xb);
    transpose_cast_kernel<<<dim3(32, 32, 4), dim3(32, 8), 0, stream>>>(
        wq, wk, wv, wo, wqT, wkT, wvT, woT);
    gemm_qkv_kernel<<<dim3(32, 8, 3), 256, 0, stream>>>(xb, wqT, wkT, wvT, bq, bk, bv, Qb, Kb, Vtb);
    attn_kernel<<<1024, 256, 0, stream>>>(Qb, Kb, Vtb, Ab);
    gemm_out_kernel<<<dim3(32, 16), 256, 0, stream>>>(Ab, woT, bo, out);
}

// Round 3
// 189.942 us; speedup vs baseline: 1.0334x; 1.0334x over previous
//
#include <hip/hip_runtime.h>
#include <hip/hip_bf16.h>

// MHA fwd: B=2, S=2048, D=1024, H=16, HD=64. fp32 in/out, bf16 MFMA internals.
// R13: R12's GEMM widening REVERTED (it regressed: thin-K shape is
// latency-bound, occupancy > per-wave MFMA density — MfmaUtil 20%, Occ 14.7%).
// GEMMs back to R10 geometry: qkv 128x64 @ (32,16,3), out 64x64 @ (64,16).
// Attn: T14 async-STAGE split — next tile's K/V loaded to REGISTERS before
// compute (latency hides under 36-MFMA phase), ds_write_b128 to LDS after the
// barrier. Replaces the serial per-tile vmcnt(0) drain. LDS content/layout
// identical to the glds path; reads untouched.

typedef __bf16 bf16x8 __attribute__((ext_vector_type(8)));
typedef float f32x4 __attribute__((ext_vector_type(4)));

#define S_LEN 2048
#define DMODEL 1024
#define NHEAD 16
#define HDIM 64
#define MROWS 4096  // B*S

#define AS1 __attribute__((address_space(1)))
#define AS3 __attribute__((address_space(3)))

#define QSCALE 0.18033688f  // 0.125 * log2e: scores come out in log2 units
#define LDP 136             // Ps row pitch (bf16): 272 B = 17x16B

// ---------------- cast x (fp32 -> bf16), 4 elems/thread ----------------
__global__ void cast_x_kernel(const float* __restrict__ X, __bf16* __restrict__ Xb) {
    int i = (blockIdx.x * blockDim.x + threadIdx.x) * 4;
    float4 f = *(const float4*)&X[i];
    Xb[i + 0] = (__bf16)f.x;
    Xb[i + 1] = (__bf16)f.y;
    Xb[i + 2] = (__bf16)f.z;
    Xb[i + 3] = (__bf16)f.w;
}

// ------------- transpose + cast all 4 weights: WT[n][k] = W[k][n] -------------
__global__ void transpose_cast_kernel(
    const float* __restrict__ W0, const float* __restrict__ W1,
    const float* __restrict__ W2, const float* __restrict__ W3,
    __bf16* __restrict__ T0, __bf16* __restrict__ T1,
    __bf16* __restrict__ T2, __bf16* __restrict__ T3) {
    const float* W = (blockIdx.z == 0) ? W0 : (blockIdx.z == 1) ? W1 : (blockIdx.z == 2) ? W2 : W3;
    __bf16* WT = (blockIdx.z == 0) ? T0 : (blockIdx.z == 1) ? T1 : (blockIdx.z == 2) ? T2 : T3;
    __shared__ float tile[32][33];
    int bx = blockIdx.x, by = blockIdx.y;
    int tx = threadIdx.x;
    for (int i = threadIdx.y; i < 32; i += 8)
        tile[i][tx] = W[(size_t)(by * 32 + i) * DMODEL + bx * 32 + tx];
    __syncthreads();
    for (int i = threadIdx.y; i < 32; i += 8)
        WT[(size_t)(bx * 32 + i) * DMODEL + by * 32 + tx] = (__bf16)tile[tx][i];
}

// ------------- GEMM QKV: 128x64 tile, BK=64, glds(16B) + XOR swizzle ---------
__global__ __launch_bounds__(256) void gemm_qkv_kernel(
    const __bf16* __restrict__ X,
    const __bf16* __restrict__ WqT, const __bf16* __restrict__ WkT, const __bf16* __restrict__ WvT,
    const float* __restrict__ bq, const float* __restrict__ bk, const float* __restrict__ bv,
    __bf16* __restrict__ Q, __bf16* __restrict__ K, __bf16* __restrict__ Vt) {
    const int which = blockIdx.z;
    const __bf16* Bt = (which == 0) ? WqT : (which == 1) ? WkT : WvT;
    const float* bias = (which == 0) ? bq : (which == 1) ? bk : bv;
    __bf16* Out = (which == 0) ? Q : (which == 1) ? K : Vt;

    __shared__ alignas(16) __bf16 As[128 * 64];
    __shared__ alignas(16) __bf16 Bs[64 * 64];

    const int tid = threadIdx.x;
    const int lane = tid & 63;
    const int wave = tid >> 6;
    const int wm = wave >> 1, wn = wave & 1;
    const int quad = lane >> 4;
    const int l16 = lane & 15;
    const int m0 = blockIdx.x * 128;   // m-tile on x (XCD locality)
    const int n0 = blockIdx.y * 64;
    const int r8 = lane >> 3;
    const int sc8 = ((lane & 7) ^ r8) * 8;
    const int gq0 = ((0 + quad) ^ (l16 & 7)) * 8;
    const int gq1 = ((4 + quad) ^ (l16 & 7)) * 8;

    f32x4 acc[4][2] = {};

    for (int k0 = 0; k0 < DMODEL; k0 += 64) {
        __syncthreads();
#pragma unroll
        for (int p = 0; p < 4; p++) {  // A: 128 rows
            const int row = wave * 32 + p * 8;
            __builtin_amdgcn_global_load_lds(
                (const AS1 void*)&X[(size_t)(m0 + row + r8) * DMODEL + k0 + sc8],
                (AS3 void*)&As[row * 64], 16, 0, 0);
        }
#pragma unroll
        for (int p = 0; p < 2; p++) {  // B: 64 rows
            const int row = wave * 16 + p * 8;
            __builtin_amdgcn_global_load_lds(
                (const AS1 void*)&Bt[(size_t)(n0 + row + r8) * DMODEL + k0 + sc8],
                (AS3 void*)&Bs[row * 64], 16, 0, 0);
        }
        __syncthreads();
#pragma unroll
        for (int ks = 0; ks < 2; ks++) {
            const int g = ks ? gq1 : gq0;
            bf16x8 af[4], bfr[2];
#pragma unroll
            for (int t = 0; t < 4; t++)
                af[t] = *(bf16x8*)&As[(wm * 64 + t * 16 + l16) * 64 + g];
#pragma unroll
            for (int t = 0; t < 2; t++)
                bfr[t] = *(bf16x8*)&Bs[(wn * 32 + t * 16 + l16) * 64 + g];
#pragma unroll
            for (int mt = 0; mt < 4; mt++)
#pragma unroll
                for (int nt = 0; nt < 2; nt++)
                    acc[mt][nt] = __builtin_amdgcn_mfma_f32_16x16x32_bf16(af[mt], bfr[nt], acc[mt][nt], 0, 0, 0);
        }
    }

    // C/D layout: col = lane&15, row = quad*4 + reg  [m89-verified]
#pragma unroll
    for (int mt = 0; mt < 4; mt++)
#pragma unroll
        for (int nt = 0; nt < 2; nt++) {
            const int n = n0 + wn * 32 + nt * 16 + l16;
            const float bn = bias[n];
            const int h = n >> 6, hd = n & 63;
            const int mbase = m0 + wm * 64 + mt * 16 + quad * 4;
            if (which == 2) {
                __bf16 pk[4];
#pragma unroll
                for (int r = 0; r < 4; r++) pk[r] = (__bf16)(acc[mt][nt][r] + bn);
                const int m = mbase;
                const int b = m >> 11, s = m & 2047;
                *(uint2*)&Out[(((size_t)(b * NHEAD + h) * HDIM + hd) * S_LEN) + s] = *(uint2*)pk;
            } else {
                const float sc = (which == 0) ? QSCALE : 1.0f;  // Q: fold 1/8 * log2e
#pragma unroll
                for (int r = 0; r < 4; r++) {
                    const int m = mbase + r;
                    const int b = m >> 11, s = m & 2047;
                    Out[(((size_t)(b * NHEAD + h) * S_LEN + s) * HDIM) + hd] =
                        (__bf16)((acc[mt][nt][r] + bn) * sc);
                }
            }
        }
}

// ------------- GEMM OUT: 64x64 tile, BK=64, grid (64,16): m-tile on x --------
__global__ __launch_bounds__(256) void gemm_out_kernel(
    const __bf16* __restrict__ A, const __bf16* __restrict__ Bt,
    const float* __restrict__ bias, float* __restrict__ Y) {
    __shared__ alignas(16) __bf16 As[64 * 64];
    __shared__ alignas(16) __bf16 Bs[64 * 64];

    const int tid = threadIdx.x;
    const int lane = tid & 63;
    const int wave = tid >> 6;
    const int wm = wave >> 1, wn = wave & 1;
    const int quad = lane >> 4;
    const int l16 = lane & 15;
    const int m0 = blockIdx.x * 64;    // m-tile on x (XCD locality)
    const int n0 = blockIdx.y * 64;
    const int r8 = lane >> 3;
    const int sc8 = ((lane & 7) ^ r8) * 8;
    const int gq0 = ((0 + quad) ^ (l16 & 7)) * 8;
    const int gq1 = ((4 + quad) ^ (l16 & 7)) * 8;

    f32x4 acc[2][2] = {};

    for (int k0 = 0; k0 < DMODEL; k0 += 64) {
        __syncthreads();
#pragma unroll
        for (int p = 0; p < 2; p++) {
            const int row = wave * 16 + p * 8;
            __builtin_amdgcn_global_load_lds(
                (const AS1 void*)&A[(size_t)(m0 + row + r8) * DMODEL + k0 + sc8],
                (AS3 void*)&As[row * 64], 16, 0, 0);
            __builtin_amdgcn_global_load_lds(
                (const AS1 void*)&Bt[(size_t)(n0 + row + r8) * DMODEL + k0 + sc8],
                (AS3 void*)&Bs[row * 64], 16, 0, 0);
        }
        __syncthreads();
#pragma unroll
        for (int ks = 0; ks < 2; ks++) {
            const int g = ks ? gq1 : gq0;
            bf16x8 af[2], bfr[2];
#pragma unroll
            for (int t = 0; t < 2; t++) {
                af[t]  = *(bf16x8*)&As[(wm * 32 + t * 16 + l16) * 64 + g];
                bfr[t] = *(bf16x8*)&Bs[(wn * 32 + t * 16 + l16) * 64 + g];
            }
#pragma unroll
            for (int mt = 0; mt < 2; mt++)
#pragma unroll
                for (int nt = 0; nt < 2; nt++)
                    acc[mt][nt] = __builtin_amdgcn_mfma_f32_16x16x32_bf16(af[mt], bfr[nt], acc[mt][nt], 0, 0, 0);
        }
    }

#pragma unroll
    for (int mt = 0; mt < 2; mt++)
#pragma unroll
        for (int nt = 0; nt < 2; nt++)
#pragma unroll
            for (int r = 0; r < 4; r++) {
                int m = m0 + wm * 32 + mt * 16 + quad * 4 + r;
                int n = n0 + wn * 32 + nt * 16 + l16;
                Y[(size_t)m * DMODEL + n] = acc[mt][nt][r] + bias[n];
            }
}

// -------- flash attention (R13: T14 async reg-staged K/V) --------------------
// Ks[128 k-rows][64 hd], Vs[64 hd][128 k-cols], Ps pitch 136. LDS content
// identical to the R10 glds path (write-side lane mapping reproduces the
// glds linear-dest rule); compute/reads untouched. Next tile's K/V loads are
// issued to registers BEFORE compute so global latency hides under MFMA.

template <int NT>
__device__ __forceinline__ void attn_tile(
    const __bf16* Ks, const __bf16* Vs, __bf16* Psw,
    const bf16x8& qf0, const bf16x8& qf1, const bf16x8& onef,
    f32x4 (&oacc)[4], f32x4& lacc,
    int q0, int k0, bool mask, int wave, int quad, int l16, int g0, int g1) {
    f32x4 sacc[NT];
#pragma unroll
    for (int nt = 0; nt < NT; nt++) sacc[nt] = (f32x4){0.f, 0.f, 0.f, 0.f};
#pragma unroll
    for (int nt = 0; nt < NT; nt++) {
        const int krow = (nt * 16 + l16) * 64;
        bf16x8 kf0 = *(bf16x8*)&Ks[krow + g0];
        bf16x8 kf1 = *(bf16x8*)&Ks[krow + g1];
        sacc[nt] = __builtin_amdgcn_mfma_f32_16x16x32_bf16(qf0, kf0, sacc[nt], 0, 0, 0);
        sacc[nt] = __builtin_amdgcn_mfma_f32_16x16x32_bf16(qf1, kf1, sacc[nt], 0, 0, 0);
    }
    if (mask) {
#pragma unroll
        for (int nt = 0; nt < NT; nt++)
#pragma unroll
            for (int r = 0; r < 4; r++) {
                const int kcol = k0 + nt * 16 + l16;
                const int qg = q0 + wave * 16 + quad * 4 + r;
                float p = (kcol > qg) ? 0.0f : __builtin_amdgcn_exp2f(sacc[nt][r]);
                Psw[(quad * 4 + r) * LDP + nt * 16 + l16] = (__bf16)p;
            }
    } else {
#pragma unroll
        for (int nt = 0; nt < NT; nt++)
#pragma unroll
            for (int r = 0; r < 4; r++)
                Psw[(quad * 4 + r) * LDP + nt * 16 + l16] =
                    (__bf16)__builtin_amdgcn_exp2f(sacc[nt][r]);
    }
#pragma unroll
    for (int ks = 0; ks < NT / 2; ks++) {
        bf16x8 pf = *(bf16x8*)&Psw[l16 * LDP + ks * 32 + quad * 8];
        const int vg = (((ks * 4 + quad) ^ (l16 & 7)) * 8);
#pragma unroll
        for (int nt2 = 0; nt2 < 4; nt2++) {
            bf16x8 vf = *(bf16x8*)&Vs[(nt2 * 16 + l16) * 128 + vg];
            oacc[nt2] = __builtin_amdgcn_mfma_f32_16x16x32_bf16(pf, vf, oacc[nt2], 0, 0, 0);
        }
        lacc = __builtin_amdgcn_mfma_f32_16x16x32_bf16(pf, onef, lacc, 0, 0, 0);
    }
}

__global__ __launch_bounds__(256, 3) void attn_kernel(
    const __bf16* __restrict__ Q, const __bf16* __restrict__ K, const __bf16* __restrict__ Vt,
    __bf16* __restrict__ Aout) {
    const int id = blockIdx.x;
    const int bh = id & 31;                 // XCD-pinned: id%8 == bh%8
    const int qt = 31 - (id >> 5);          // big tiles first
    const int b = bh >> 4, h = bh & 15;
    const int tid = threadIdx.x, lane = tid & 63, wave = tid >> 6;
    const int quad = lane >> 4, l16 = lane & 15;

    __shared__ alignas(16) __bf16 Ks[128 * 64];
    __shared__ alignas(16) __bf16 Vs[64 * 128];
    __shared__ alignas(16) __bf16 Ps[4][16 * LDP];

    const size_t base = (size_t)bh * S_LEN * HDIM;   // same for K and Vt
    const int q0 = qt * 64;
    const int qrow = q0 + wave * 16 + l16;

    bf16x8 qf0 = *(const bf16x8*)&Q[base + (size_t)qrow * HDIM + quad * 8];
    bf16x8 qf1 = *(const bf16x8*)&Q[base + (size_t)qrow * HDIM + 32 + quad * 8];

    bf16x8 onef;
#pragma unroll
    for (int jj = 0; jj < 8; jj++) onef[jj] = (__bf16)1.0f;

    f32x4 oacc[4] = {};
    f32x4 lacc = {};
    __bf16* Psw = &Ps[wave][0];

    // staging lane roles (reg-stage; mapping reproduces glds linear-dest rule)
    const int kr = lane >> 3;                 // K: row within 8-row group
    const int kc = ((lane & 7) ^ kr) * 8;     // K: swizzled source chunk (elems)
    const int kwc = (lane & 7) * 8;           // K: linear LDS dest chunk
    const int vr = lane >> 4;                 // V: row within 4-row group
    const int vwc = (lane & 15) * 8;          // V: linear LDS dest chunk
    // fragment-read granules (Ks pitch 64)
    const int g0 = (quad ^ (l16 & 7)) * 8;
    const int g1 = g0 ^ 32;

    const int kb_all = (qt >> 1) + 1;

    bf16x8 kreg[4], vreg[4];
    // prologue: load tile 0 into registers
#pragma unroll
    for (int p = 0; p < 4; p++) {
        const int row = wave * 32 + p * 8 + kr;
        kreg[p] = *(const bf16x8*)&K[base + (size_t)row * HDIM + kc];
    }
#pragma unroll
    for (int p = 0; p < 4; p++) {
        const int vrow = wave * 16 + p * 4 + vr;
        const int lc = ((lane & 15) ^ ((p * 4 + vr) & 7)) * 8;
        vreg[p] = *(const bf16x8*)&Vt[base + (size_t)vrow * S_LEN + lc];
    }

    for (int kb = 0; kb < kb_all; kb++) {
        const int k0 = kb * 128;
        __syncthreads();   // all waves done reading previous LDS tile
        // ds_write staged regs -> LDS (same content/layout as glds path)
#pragma unroll
        for (int p = 0; p < 4; p++) {
            const int row = wave * 32 + p * 8 + kr;
            *(bf16x8*)&Ks[row * 64 + kwc] = kreg[p];
        }
#pragma unroll
        for (int p = 0; p < 4; p++) {
            const int vrow = wave * 16 + p * 4 + vr;
            *(bf16x8*)&Vs[vrow * 128 + vwc] = vreg[p];
        }
        __syncthreads();   // writes visible to all waves
        // issue next tile's loads now; latency hides under compute below
        if (kb + 1 < kb_all) {
            const int k1 = k0 + 128;
#pragma unroll
            for (int p = 0; p < 4; p++) {
                const int row = wave * 32 + p * 8 + kr;
                kreg[p] = *(const bf16x8*)&K[base + (size_t)(k1 + row) * HDIM + kc];
            }
#pragma unroll
            for (int p = 0; p < 4; p++) {
                const int vrow = wave * 16 + p * 4 + vr;
                const int lc = ((lane & 15) ^ ((p * 4 + vr) & 7)) * 8;
                vreg[p] = *(const bf16x8*)&Vt[base + (size_t)vrow * S_LEN + k1 + lc];
            }
        }

        const bool last = (kb == kb_all - 1);
        if (!last)
            attn_tile<8>(Ks, Vs, Psw, qf0, qf1, onef, oacc, lacc, q0, k0, false,
                         wave, quad, l16, g0, g1);
        else if (qt & 1)
            attn_tile<8>(Ks, Vs, Psw, qf0, qf1, onef, oacc, lacc, q0, k0, true,
                         wave, quad, l16, g0, g1);
        else
            attn_tile<4>(Ks, Vs, Psw, qf0, qf1, onef, oacc, lacc, q0, k0, true,
                         wave, quad, l16, g0, g1);
    }

    float rl[4];
#pragma unroll
    for (int r = 0; r < 4; r++) rl[r] = 1.0f / lacc[r];
#pragma unroll
    for (int nt2 = 0; nt2 < 4; nt2++)
#pragma unroll
        for (int r = 0; r < 4; r++) {
            int qg = q0 + wave * 16 + quad * 4 + r;
            int col = h * HDIM + nt2 * 16 + l16;
            Aout[(size_t)(b * S_LEN + qg) * DMODEL + col] = (__bf16)(oacc[nt2][r] * rl[r]);
        }
}

extern "C" void kernel_launch(void* const* d_in, const int* in_sizes, int n_in,
                              void* d_out, int out_size, void* d_ws, size_t ws_size,
                              hipStream_t stream) {
    const float* x  = (const float*)d_in[0];
    // d_in[1] = mask: causal triu, reproduced analytically
    const float* wq = (const float*)d_in[2];
    const float* bq = (const float*)d_in[3];
    const float* wk = (const float*)d_in[4];
    const float* bk = (const float*)d_in[5];
    const float* wv = (const float*)d_in[6];
    const float* bv = (const float*)d_in[7];
    const float* wo = (const float*)d_in[8];
    const float* bo = (const float*)d_in[9];
    float* out = (float*)d_out;

    char* ws = (char*)d_ws;
    __bf16* xb  = (__bf16*)(ws);                          // 8 MiB
    __bf16* wqT = (__bf16*)(ws + ((size_t)8  << 20));     // 2 MiB each
    __bf16* wkT = (__bf16*)(ws + ((size_t)10 << 20));
    __bf16* wvT = (__bf16*)(ws + ((size_t)12 << 20));
    __bf16* woT = (__bf16*)(ws + ((size_t)14 << 20));
    __bf16* Qb  = (__bf16*)(ws + ((size_t)16 << 20));     // 8 MiB each
    __bf16* Kb  = (__bf16*)(ws + ((size_t)24 << 20));
    __bf16* Vtb = (__bf16*)(ws + ((size_t)32 << 20));     // V^T [B,H,HD,S]
    __bf16* Ab  = (__bf16*)(ws + ((size_t)40 << 20));     // 8 MiB

    cast_x_kernel<<<4096, 256, 0, stream>>>(x, xb);
    transpose_cast_kernel<<<dim3(32, 32, 4), dim3(32, 8), 0, stream>>>(
        wq, wk, wv, wo, wqT, wkT, wvT, woT);
    gemm_qkv_kernel<<<dim3(32, 16, 3), 256, 0, stream>>>(xb, wqT, wkT, wvT, bq, bk, bv, Qb, Kb, Vtb);
    attn_kernel<<<1024, 256, 0, stream>>>(Qb, Kb, Vtb, Ab);
    gemm_out_kernel<<<dim3(64, 16), 256, 0, stream>>>(Ab, woT, bo, out);
}

// Round 4
// 183.720 us; speedup vs baseline: 1.0684x; 1.0339x over previous
//
#include <hip/hip_runtime.h>
#include <hip/hip_bf16.h>

// MHA fwd: B=2, S=2048, D=1024, H=16, HD=64. fp32 in/out, bf16 MFMA internals.
// R14: attn staging reverted to glds (R13's reg-stage T14 regressed: 2.7M LDS
// bank conflicts from 8-way-aliased ds_writes; catalog says T14 net-negative
// where glds applies). NEW: QK^T operand swap — mfma(kf,qf) gives S^T, so each
// lane's 4 acc regs are 4 contiguous k-cols of ONE q-row (l16) -> P-store is
// one bf16x4 ds_write_b64 per nt (was 32x ds_write_b16 per tile; cvts pair
// into v_cvt_pk_bf16_f32). Ps layout + PV side unchanged.
// GEMMs: R10 geometry (qkv 128x64 @ (32,16,3), out 64x64 @ (64,16)).

typedef __bf16 bf16x8 __attribute__((ext_vector_type(8)));
typedef __bf16 bf16x4 __attribute__((ext_vector_type(4)));
typedef float f32x4 __attribute__((ext_vector_type(4)));

#define S_LEN 2048
#define DMODEL 1024
#define NHEAD 16
#define HDIM 64
#define MROWS 4096  // B*S

#define AS1 __attribute__((address_space(1)))
#define AS3 __attribute__((address_space(3)))

#define QSCALE 0.18033688f  // 0.125 * log2e: scores come out in log2 units
#define LDP 136             // Ps row pitch (bf16): 272 B = 17x16B

// ---------------- cast x (fp32 -> bf16), 4 elems/thread ----------------
__global__ void cast_x_kernel(const float* __restrict__ X, __bf16* __restrict__ Xb) {
    int i = (blockIdx.x * blockDim.x + threadIdx.x) * 4;
    float4 f = *(const float4*)&X[i];
    Xb[i + 0] = (__bf16)f.x;
    Xb[i + 1] = (__bf16)f.y;
    Xb[i + 2] = (__bf16)f.z;
    Xb[i + 3] = (__bf16)f.w;
}

// ------------- transpose + cast all 4 weights: WT[n][k] = W[k][n] -------------
__global__ void transpose_cast_kernel(
    const float* __restrict__ W0, const float* __restrict__ W1,
    const float* __restrict__ W2, const float* __restrict__ W3,
    __bf16* __restrict__ T0, __bf16* __restrict__ T1,
    __bf16* __restrict__ T2, __bf16* __restrict__ T3) {
    const float* W = (blockIdx.z == 0) ? W0 : (blockIdx.z == 1) ? W1 : (blockIdx.z == 2) ? W2 : W3;
    __bf16* WT = (blockIdx.z == 0) ? T0 : (blockIdx.z == 1) ? T1 : (blockIdx.z == 2) ? T2 : T3;
    __shared__ float tile[32][33];
    int bx = blockIdx.x, by = blockIdx.y;
    int tx = threadIdx.x;
    for (int i = threadIdx.y; i < 32; i += 8)
        tile[i][tx] = W[(size_t)(by * 32 + i) * DMODEL + bx * 32 + tx];
    __syncthreads();
    for (int i = threadIdx.y; i < 32; i += 8)
        WT[(size_t)(bx * 32 + i) * DMODEL + by * 32 + tx] = (__bf16)tile[tx][i];
}

// ------------- GEMM QKV: 128x64 tile, BK=64, glds(16B) + XOR swizzle ---------
__global__ __launch_bounds__(256) void gemm_qkv_kernel(
    const __bf16* __restrict__ X,
    const __bf16* __restrict__ WqT, const __bf16* __restrict__ WkT, const __bf16* __restrict__ WvT,
    const float* __restrict__ bq, const float* __restrict__ bk, const float* __restrict__ bv,
    __bf16* __restrict__ Q, __bf16* __restrict__ K, __bf16* __restrict__ Vt) {
    const int which = blockIdx.z;
    const __bf16* Bt = (which == 0) ? WqT : (which == 1) ? WkT : WvT;
    const float* bias = (which == 0) ? bq : (which == 1) ? bk : bv;
    __bf16* Out = (which == 0) ? Q : (which == 1) ? K : Vt;

    __shared__ alignas(16) __bf16 As[128 * 64];
    __shared__ alignas(16) __bf16 Bs[64 * 64];

    const int tid = threadIdx.x;
    const int lane = tid & 63;
    const int wave = tid >> 6;
    const int wm = wave >> 1, wn = wave & 1;
    const int quad = lane >> 4;
    const int l16 = lane & 15;
    const int m0 = blockIdx.x * 128;   // m-tile on x (XCD locality)
    const int n0 = blockIdx.y * 64;
    const int r8 = lane >> 3;
    const int sc8 = ((lane & 7) ^ r8) * 8;
    const int gq0 = ((0 + quad) ^ (l16 & 7)) * 8;
    const int gq1 = ((4 + quad) ^ (l16 & 7)) * 8;

    f32x4 acc[4][2] = {};

    for (int k0 = 0; k0 < DMODEL; k0 += 64) {
        __syncthreads();
#pragma unroll
        for (int p = 0; p < 4; p++) {  // A: 128 rows
            const int row = wave * 32 + p * 8;
            __builtin_amdgcn_global_load_lds(
                (const AS1 void*)&X[(size_t)(m0 + row + r8) * DMODEL + k0 + sc8],
                (AS3 void*)&As[row * 64], 16, 0, 0);
        }
#pragma unroll
        for (int p = 0; p < 2; p++) {  // B: 64 rows
            const int row = wave * 16 + p * 8;
            __builtin_amdgcn_global_load_lds(
                (const AS1 void*)&Bt[(size_t)(n0 + row + r8) * DMODEL + k0 + sc8],
                (AS3 void*)&Bs[row * 64], 16, 0, 0);
        }
        __syncthreads();
#pragma unroll
        for (int ks = 0; ks < 2; ks++) {
            const int g = ks ? gq1 : gq0;
            bf16x8 af[4], bfr[2];
#pragma unroll
            for (int t = 0; t < 4; t++)
                af[t] = *(bf16x8*)&As[(wm * 64 + t * 16 + l16) * 64 + g];
#pragma unroll
            for (int t = 0; t < 2; t++)
                bfr[t] = *(bf16x8*)&Bs[(wn * 32 + t * 16 + l16) * 64 + g];
#pragma unroll
            for (int mt = 0; mt < 4; mt++)
#pragma unroll
                for (int nt = 0; nt < 2; nt++)
                    acc[mt][nt] = __builtin_amdgcn_mfma_f32_16x16x32_bf16(af[mt], bfr[nt], acc[mt][nt], 0, 0, 0);
        }
    }

    // C/D layout: col = lane&15, row = quad*4 + reg  [m89-verified]
#pragma unroll
    for (int mt = 0; mt < 4; mt++)
#pragma unroll
        for (int nt = 0; nt < 2; nt++) {
            const int n = n0 + wn * 32 + nt * 16 + l16;
            const float bn = bias[n];
            const int h = n >> 6, hd = n & 63;
            const int mbase = m0 + wm * 64 + mt * 16 + quad * 4;
            if (which == 2) {
                __bf16 pk[4];
#pragma unroll
                for (int r = 0; r < 4; r++) pk[r] = (__bf16)(acc[mt][nt][r] + bn);
                const int m = mbase;
                const int b = m >> 11, s = m & 2047;
                *(uint2*)&Out[(((size_t)(b * NHEAD + h) * HDIM + hd) * S_LEN) + s] = *(uint2*)pk;
            } else {
                const float sc = (which == 0) ? QSCALE : 1.0f;  // Q: fold 1/8 * log2e
#pragma unroll
                for (int r = 0; r < 4; r++) {
                    const int m = mbase + r;
                    const int b = m >> 11, s = m & 2047;
                    Out[(((size_t)(b * NHEAD + h) * S_LEN + s) * HDIM) + hd] =
                        (__bf16)((acc[mt][nt][r] + bn) * sc);
                }
            }
        }
}

// ------------- GEMM OUT: 64x64 tile, BK=64, grid (64,16): m-tile on x --------
__global__ __launch_bounds__(256) void gemm_out_kernel(
    const __bf16* __restrict__ A, const __bf16* __restrict__ Bt,
    const float* __restrict__ bias, float* __restrict__ Y) {
    __shared__ alignas(16) __bf16 As[64 * 64];
    __shared__ alignas(16) __bf16 Bs[64 * 64];

    const int tid = threadIdx.x;
    const int lane = tid & 63;
    const int wave = tid >> 6;
    const int wm = wave >> 1, wn = wave & 1;
    const int quad = lane >> 4;
    const int l16 = lane & 15;
    const int m0 = blockIdx.x * 64;    // m-tile on x (XCD locality)
    const int n0 = blockIdx.y * 64;
    const int r8 = lane >> 3;
    const int sc8 = ((lane & 7) ^ r8) * 8;
    const int gq0 = ((0 + quad) ^ (l16 & 7)) * 8;
    const int gq1 = ((4 + quad) ^ (l16 & 7)) * 8;

    f32x4 acc[2][2] = {};

    for (int k0 = 0; k0 < DMODEL; k0 += 64) {
        __syncthreads();
#pragma unroll
        for (int p = 0; p < 2; p++) {
            const int row = wave * 16 + p * 8;
            __builtin_amdgcn_global_load_lds(
                (const AS1 void*)&A[(size_t)(m0 + row + r8) * DMODEL + k0 + sc8],
                (AS3 void*)&As[row * 64], 16, 0, 0);
            __builtin_amdgcn_global_load_lds(
                (const AS1 void*)&Bt[(size_t)(n0 + row + r8) * DMODEL + k0 + sc8],
                (AS3 void*)&Bs[row * 64], 16, 0, 0);
        }
        __syncthreads();
#pragma unroll
        for (int ks = 0; ks < 2; ks++) {
            const int g = ks ? gq1 : gq0;
            bf16x8 af[2], bfr[2];
#pragma unroll
            for (int t = 0; t < 2; t++) {
                af[t]  = *(bf16x8*)&As[(wm * 32 + t * 16 + l16) * 64 + g];
                bfr[t] = *(bf16x8*)&Bs[(wn * 32 + t * 16 + l16) * 64 + g];
            }
#pragma unroll
            for (int mt = 0; mt < 2; mt++)
#pragma unroll
                for (int nt = 0; nt < 2; nt++)
                    acc[mt][nt] = __builtin_amdgcn_mfma_f32_16x16x32_bf16(af[mt], bfr[nt], acc[mt][nt], 0, 0, 0);
        }
    }

#pragma unroll
    for (int mt = 0; mt < 2; mt++)
#pragma unroll
        for (int nt = 0; nt < 2; nt++)
#pragma unroll
            for (int r = 0; r < 4; r++) {
                int m = m0 + wm * 32 + mt * 16 + quad * 4 + r;
                int n = n0 + wn * 32 + nt * 16 + l16;
                Y[(size_t)m * DMODEL + n] = acc[mt][nt][r] + bias[n];
            }
}

// -------- flash attention (R14: glds staging + swapped QK^T) -----------------
// Ks[128 k-rows][64 hd], Vs[64 hd][128 k-cols], Ps pitch 136.
// QK computed as mfma(kf, qf) -> S^T in regs: lane's D col (l16) = q-row,
// D rows (quad*4+r) = 4 contiguous k-cols -> P-store packs to bf16x4 b64.
// Ps layout in LDS unchanged: P[qrow=l16? no: row l16][kcol] — row-major
// [16 q][128 k]; PV read side identical to R10.

template <int NT>
__device__ __forceinline__ void attn_tile(
    const __bf16* Ks, const __bf16* Vs, __bf16* Psw,
    const bf16x8& qf0, const bf16x8& qf1, const bf16x8& onef,
    f32x4 (&oacc)[4], f32x4& lacc,
    int q0, int k0, bool mask, int wave, int quad, int l16, int g0, int g1) {
    f32x4 sacc[NT];
#pragma unroll
    for (int nt = 0; nt < NT; nt++) sacc[nt] = (f32x4){0.f, 0.f, 0.f, 0.f};
#pragma unroll
    for (int nt = 0; nt < NT; nt++) {
        const int krow = (nt * 16 + l16) * 64;
        bf16x8 kf0 = *(bf16x8*)&Ks[krow + g0];
        bf16x8 kf1 = *(bf16x8*)&Ks[krow + g1];
        // swapped: A=K rows, B=Q rows -> D = S^T
        sacc[nt] = __builtin_amdgcn_mfma_f32_16x16x32_bf16(kf0, qf0, sacc[nt], 0, 0, 0);
        sacc[nt] = __builtin_amdgcn_mfma_f32_16x16x32_bf16(kf1, qf1, sacc[nt], 0, 0, 0);
    }
    // lane holds q-row (q0+wave*16+l16), k-cols k0+nt*16+quad*4+r (r=0..3)
    const int qg = q0 + wave * 16 + l16;
    if (mask) {
#pragma unroll
        for (int nt = 0; nt < NT; nt++) {
            bf16x4 pv;
#pragma unroll
            for (int r = 0; r < 4; r++) {
                const int kcol = k0 + nt * 16 + quad * 4 + r;
                pv[r] = (__bf16)((kcol > qg) ? 0.0f : __builtin_amdgcn_exp2f(sacc[nt][r]));
            }
            *(bf16x4*)&Psw[l16 * LDP + nt * 16 + quad * 4] = pv;
        }
    } else {
#pragma unroll
        for (int nt = 0; nt < NT; nt++) {
            bf16x4 pv;
#pragma unroll
            for (int r = 0; r < 4; r++)
                pv[r] = (__bf16)__builtin_amdgcn_exp2f(sacc[nt][r]);
            *(bf16x4*)&Psw[l16 * LDP + nt * 16 + quad * 4] = pv;
        }
    }
#pragma unroll
    for (int ks = 0; ks < NT / 2; ks++) {
        bf16x8 pf = *(bf16x8*)&Psw[l16 * LDP + ks * 32 + quad * 8];
        const int vg = (((ks * 4 + quad) ^ (l16 & 7)) * 8);
#pragma unroll
        for (int nt2 = 0; nt2 < 4; nt2++) {
            bf16x8 vf = *(bf16x8*)&Vs[(nt2 * 16 + l16) * 128 + vg];
            oacc[nt2] = __builtin_amdgcn_mfma_f32_16x16x32_bf16(pf, vf, oacc[nt2], 0, 0, 0);
        }
        lacc = __builtin_amdgcn_mfma_f32_16x16x32_bf16(pf, onef, lacc, 0, 0, 0);
    }
}

__global__ __launch_bounds__(256, 3) void attn_kernel(
    const __bf16* __restrict__ Q, const __bf16* __restrict__ K, const __bf16* __restrict__ Vt,
    __bf16* __restrict__ Aout) {
    const int id = blockIdx.x;
    const int bh = id & 31;                 // XCD-pinned: id%8 == bh%8
    const int qt = 31 - (id >> 5);          // big tiles first
    const int b = bh >> 4, h = bh & 15;
    const int tid = threadIdx.x, lane = tid & 63, wave = tid >> 6;
    const int quad = lane >> 4, l16 = lane & 15;

    __shared__ alignas(16) __bf16 Ks[128 * 64];
    __shared__ alignas(16) __bf16 Vs[64 * 128];
    __shared__ alignas(16) __bf16 Ps[4][16 * LDP];

    const size_t base = (size_t)bh * S_LEN * HDIM;   // same for K and Vt
    const int q0 = qt * 64;
    const int qrow = q0 + wave * 16 + l16;

    bf16x8 qf0 = *(const bf16x8*)&Q[base + (size_t)qrow * HDIM + quad * 8];
    bf16x8 qf1 = *(const bf16x8*)&Q[base + (size_t)qrow * HDIM + 32 + quad * 8];

    bf16x8 onef;
#pragma unroll
    for (int jj = 0; jj < 8; jj++) onef[jj] = (__bf16)1.0f;

    f32x4 oacc[4] = {};
    f32x4 lacc = {};
    __bf16* Psw = &Ps[wave][0];

    // staging lane roles
    const int r8k = lane >> 3;
    const int sck = ((lane & 7) ^ r8k) * 8;          // K source chunk (elems)
    const int r4v = lane >> 4;                        // V: 4 rows per glds
    // fragment-read granules (Ks pitch 64)
    const int g0 = (quad ^ (l16 & 7)) * 8;
    const int g1 = g0 ^ 32;

    const int kb_all = (qt >> 1) + 1;
    for (int kb = 0; kb < kb_all; kb++) {
        const int k0 = kb * 128;
        __syncthreads();
#pragma unroll
        for (int p = 0; p < 4; p++) {  // K: 128 rows, 8 rows/glds
            const int row = wave * 32 + p * 8;
            __builtin_amdgcn_global_load_lds(
                (const AS1 void*)&K[base + (size_t)(k0 + row + r8k) * HDIM + sck],
                (AS3 void*)&Ks[row * 64], 16, 0, 0);
        }
#pragma unroll
        for (int p = 0; p < 4; p++) {  // V^T: 64 rows x 128 cols, 4 rows/glds
            const int row = wave * 16 + p * 4;
            const int lc = ((lane & 15) ^ ((p * 4 + r4v) & 7)) * 8;
            __builtin_amdgcn_global_load_lds(
                (const AS1 void*)&Vt[base + (size_t)(row + r4v) * S_LEN + k0 + lc],
                (AS3 void*)&Vs[row * 128], 16, 0, 0);
        }
        __syncthreads();

        const bool last = (kb == kb_all - 1);
        if (!last)
            attn_tile<8>(Ks, Vs, Psw, qf0, qf1, onef, oacc, lacc, q0, k0, false,
                         wave, quad, l16, g0, g1);
        else if (qt & 1)
            attn_tile<8>(Ks, Vs, Psw, qf0, qf1, onef, oacc, lacc, q0, k0, true,
                         wave, quad, l16, g0, g1);
        else
            attn_tile<4>(Ks, Vs, Psw, qf0, qf1, onef, oacc, lacc, q0, k0, true,
                         wave, quad, l16, g0, g1);
    }

    float rl[4];
#pragma unroll
    for (int r = 0; r < 4; r++) rl[r] = 1.0f / lacc[r];
#pragma unroll
    for (int nt2 = 0; nt2 < 4; nt2++)
#pragma unroll
        for (int r = 0; r < 4; r++) {
            int qg = q0 + wave * 16 + quad * 4 + r;
            int col = h * HDIM + nt2 * 16 + l16;
            Aout[(size_t)(b * S_LEN + qg) * DMODEL + col] = (__bf16)(oacc[nt2][r] * rl[r]);
        }
}

extern "C" void kernel_launch(void* const* d_in, const int* in_sizes, int n_in,
                              void* d_out, int out_size, void* d_ws, size_t ws_size,
                              hipStream_t stream) {
    const float* x  = (const float*)d_in[0];
    // d_in[1] = mask: causal triu, reproduced analytically
    const float* wq = (const float*)d_in[2];
    const float* bq = (const float*)d_in[3];
    const float* wk = (const float*)d_in[4];
    const float* bk = (const float*)d_in[5];
    const float* wv = (const float*)d_in[6];
    const float* bv = (const float*)d_in[7];
    const float* wo = (const float*)d_in[8];
    const float* bo = (const float*)d_in[9];
    float* out = (float*)d_out;

    char* ws = (char*)d_ws;
    __bf16* xb  = (__bf16*)(ws);                          // 8 MiB
    __bf16* wqT = (__bf16*)(ws + ((size_t)8  << 20));     // 2 MiB each
    __bf16* wkT = (__bf16*)(ws + ((size_t)10 << 20));
    __bf16* wvT = (__bf16*)(ws + ((size_t)12 << 20));
    __bf16* woT = (__bf16*)(ws + ((size_t)14 << 20));
    __bf16* Qb  = (__bf16*)(ws + ((size_t)16 << 20));     // 8 MiB each
    __bf16* Kb  = (__bf16*)(ws + ((size_t)24 << 20));
    __bf16* Vtb = (__bf16*)(ws + ((size_t)32 << 20));     // V^T [B,H,HD,S]
    __bf16* Ab  = (__bf16*)(ws + ((size_t)40 << 20));     // 8 MiB

    cast_x_kernel<<<4096, 256, 0, stream>>>(x, xb);
    transpose_cast_kernel<<<dim3(32, 32, 4), dim3(32, 8), 0, stream>>>(
        wq, wk, wv, wo, wqT, wkT, wvT, woT);
    gemm_qkv_kernel<<<dim3(32, 16, 3), 256, 0, stream>>>(xb, wqT, wkT, wvT, bq, bk, bv, Qb, Kb, Vtb);
    attn_kernel<<<1024, 256, 0, stream>>>(Qb, Kb, Vtb, Ab);
    gemm_out_kernel<<<dim3(64, 16), 256, 0, stream>>>(Ab, woT, bo, out);
}